// Round 3
// baseline (353.478 us; speedup 1.0000x reference)
//
#include <hip/hip_runtime.h>
#include <math.h>

// Problem constants
#define NF 5
#define NB 8
#define NC 64
#define HW 16384
#define NK 320               // NF*NC
#define FSTRIDE (NB*NC*HW)   // elements per frame = 8388608

// ws layout (floats)
#define EN_FLOATS    (NB*NC*8)   // 4096: per (b,c): E0..E3, N0..N3

// ---------------- k0: pack origin_w [64][320] -> Wp[c>>2][k=320][4]; zero EN ----
// k1's wave owns 4 channels; its W slice is 320 contiguous 4-float rows (5 KB)
// -> wave-uniform addresses -> scalar (s_load) weight reads.
// Block 80 zeroes EN (replaces the hipMemsetAsync dispatch).
__global__ void k0_wp(const float* __restrict__ W, float* __restrict__ Wp,
                      float* __restrict__ EN){
    const int blk = blockIdx.x, tid = threadIdx.x;
    if (blk == 80){
        float4 z = make_float4(0.f,0.f,0.f,0.f);
#pragma unroll
        for (int j=0; j<4; ++j)
            reinterpret_cast<float4*>(EN)[tid*4 + j] = z;
        return;
    }
    int idx = blk*256 + tid;          // 0..20479 == NC*NK
    int c = idx / NK;
    int k = idx - c*NK;
    Wp[((c>>2)*NK + k)*4 + (c&3)] = W[idx];
}

__device__ __forceinline__ float redsum64(float v){
#pragma unroll
    for (int m = 1; m < 64; m <<= 1) v += __shfl_xor(v, m, 64);
    return v;
}

// ---------------- k1: fused GEMM + E/N, occupancy-first design ----------------
// v3 diagnosis: rounds 1-2 both pinned at VALUBusy ~37% / occupancy 38% with
// grid 512 = 2 blocks/CU -- latency-bound, not weight-path-bound. Fix: 2048
// blocks x 256 thr = 8 blocks/CU = 8 waves/SIMD. Channels split 4-ways across
// blocks (cgrp); the 4 blocks sharing one X panel are pinned to the SAME XCD
// (consecutive blk>>3 slots under blk%8 round-robin) so the 4x logical X read
// is served by that XCD's L2 -- HBM fetch stays ~= input size.
// Wave owns 4 channels (16 acc VGPRs); lane owns 4 spatial floats (float4,
// 16B/lane). Per k: 1 coalesced float4 X load + 4 scalar weight floats
// (s_load_dwordx4, uniform) + 16 FMAs. No LDS, no barriers.
// Phase B in-register: dot accs vs (x4-xi), 6-step shfl_xor butterflies,
// lane 0 atomics into EN.
__global__ __launch_bounds__(256, 8) void k1_fused(
    const float* __restrict__ inp, const float* __restrict__ Wp,
    const float* __restrict__ bias, float* __restrict__ EN)
{
    const int tid = threadIdx.x;
    const int l   = tid & 63;                                   // lane
    const int wv  = __builtin_amdgcn_readfirstlane(tid >> 6);   // wave 0..3
    const int blk = blockIdx.x;
    // XCD-pairing swizzle: 4 consecutive slots (same XCD) share one (b,swin).
    const int xcd  = blk & 7;
    const int slot = blk >> 3;          // 0..255
    const int cgrp = slot & 3;          // which 16-channel group
    const int g    = xcd*64 + (slot >> 2);   // 0..511 = (b, swin)
    const int b    = g >> 6;
    const int s0   = (g & 63) << 8;     // 256-float window
    const int c0   = (cgrp << 4) + (wv << 2);                   // first of 4 channels
    const int sl   = __builtin_amdgcn_readfirstlane(c0 >> 2);   // W slice 0..15

    // ---- accumulators, bias-initialized ----
    float4 a0,a1,a2,a3;
    {
        float4 bv = *reinterpret_cast<const float4*>(bias + c0);
        a0 = make_float4(bv.x,bv.x,bv.x,bv.x);
        a1 = make_float4(bv.y,bv.y,bv.y,bv.y);
        a2 = make_float4(bv.z,bv.z,bv.z,bv.z);
        a3 = make_float4(bv.w,bv.w,bv.w,bv.w);
    }

    const float* wsl = Wp + (size_t)sl * (NK*4);    // this wave's 5 KB W slice

#define FMA4(A, WS) \
    A.x = fmaf(WS, xv.x, A.x); A.y = fmaf(WS, xv.y, A.y); \
    A.z = fmaf(WS, xv.z, A.z); A.w = fmaf(WS, xv.w, A.w);

#pragma unroll 1
    for (int f=0; f<NF; ++f){
        const float* xp = inp + (size_t)(f*NB + b)*NC*HW + s0 + (l << 2);
        const float* wf = wsl + f*256;              // 64 k x 4 floats
#pragma unroll 8
        for (int k=0; k<64; ++k){
            float4 xv = *reinterpret_cast<const float4*>(xp);
            xp += HW;
            float4 w  = *reinterpret_cast<const float4*>(wf + (k << 2)); // s_load
            FMA4(a0, w.x) FMA4(a1, w.y) FMA4(a2, w.z) FMA4(a3, w.w)
        }
    }
#undef FMA4

    // ---- Phase B: in-register E/N for this wave's 4 channels ----
    // E[b,c,i] = sum_s o[c,s]*(x4[c,s]-xi[c,s]);  N[b,c,i] = sum_s (x4-xi)^2
#define PHASEB(CC, ACC) { \
    const float* cb = inp + ((size_t)b*NC + (c0+(CC)))*HW + s0 + (l << 2); \
    float4 x4 = *reinterpret_cast<const float4*>(cb + (size_t)4*FSTRIDE); \
    float ev[4], nv[4]; \
    _Pragma("unroll") \
    for (int i=0; i<4; ++i){ \
        float4 xi = *reinterpret_cast<const float4*>(cb + (size_t)i*FSTRIDE); \
        float dx = x4.x - xi.x, dy = x4.y - xi.y; \
        float dz = x4.z - xi.z, dw = x4.w - xi.w; \
        nv[i] = fmaf(dx,dx, fmaf(dy,dy, fmaf(dz,dz, dw*dw))); \
        ev[i] = fmaf((ACC).x,dx, fmaf((ACC).y,dy, fmaf((ACC).z,dz, (ACC).w*dw))); \
    } \
    _Pragma("unroll") \
    for (int i=0; i<4; ++i){ ev[i] = redsum64(ev[i]); nv[i] = redsum64(nv[i]); } \
    if (l == 0){ \
        float* p = EN + ((size_t)b*NC + c0 + (CC))*8; \
        atomicAdd(p+0, ev[0]); atomicAdd(p+1, ev[1]); \
        atomicAdd(p+2, ev[2]); atomicAdd(p+3, ev[3]); \
        atomicAdd(p+4, nv[0]); atomicAdd(p+5, nv[1]); \
        atomicAdd(p+6, nv[2]); atomicAdd(p+7, nv[3]); \
    } }

    PHASEB(0, a0) PHASEB(1, a1) PHASEB(2, a2) PHASEB(3, a3)
#undef PHASEB
}

// ---------------- k3: finalize coefs (inlined k2) + y = alpha . inp + out_b ----
// 512 blocks x 512 thr (2 blocks/CU, 16 waves/CU). Prologue: 64 lanes
// recompute the 320 alpha coefs from EN per block (trivial, removes the k2
// dispatch and its drain bubble). Main loop: wave rg owns 40 of 320 rows,
// alpha via uniform LDS broadcast, float4 (16B/lane) coalesced X loads,
// unroll 8. One LDS tree reduces the 8-way row split; direct float4 store.
__global__ __launch_bounds__(512) void k3_out(const float* __restrict__ inp,
        const float* __restrict__ EN, const float* __restrict__ out_w,
        const float* __restrict__ out_b, float* __restrict__ y)
{
    __shared__ float  Al[NK];
    __shared__ float4 P[512];
    const int tid = threadIdx.x;
    const int b   = blockIdx.x >> 6;
    const int s0  = (blockIdx.x & 63) << 8;                     // 256-float window
    const int sg  = tid & 63;
    const int rg  = __builtin_amdgcn_readfirstlane(tid >> 6);   // 0..7: 40-row group

    if (tid < 64){          // inline k2: coefs for channel c = tid
        const int c = tid;
        const float* e = EN + ((size_t)b*NC + c)*8;
        float w1 = out_w[c], w2 = out_w[NC + c];
        float csum = 0.f;
#pragma unroll
        for (int i=0; i<4; ++i){
            float nc = fmaxf(sqrtf(e[4+i]), 1e-12f);
            float coef = e[i] / (nc*nc);
            Al[i*NC + c] = -w1*coef;
            csum += coef;
        }
        Al[4*NC + c] = w1*csum + w2;
    }
    __syncthreads();

    float4 acc = make_float4(0.f, 0.f, 0.f, 0.f);
    const int rbase = rg*40;
#pragma unroll 8
    for (int j=0; j<40; ++j){
        int r = rbase + j;                                      // uniform per wave
        const float* p = inp + (size_t)(((r>>6)*NB + b)*NC + (r&63))*HW + s0 + (sg<<2);
        float  w  = Al[r];                                      // uniform LDS broadcast
        float4 xv = *reinterpret_cast<const float4*>(p);
        acc.x = fmaf(w, xv.x, acc.x); acc.y = fmaf(w, xv.y, acc.y);
        acc.z = fmaf(w, xv.z, acc.z); acc.w = fmaf(w, xv.w, acc.w);
    }
    P[tid] = acc;
    __syncthreads();
    if (tid < 64){
        float4 r0 = P[tid];
        float vx = r0.x, vy = r0.y, vz = r0.z, vw = r0.w;
#pragma unroll
        for (int gg=1; gg<8; ++gg){
            float4 q = P[tid + (gg<<6)];
            vx += q.x; vy += q.y; vz += q.z; vw += q.w;
        }
        float bb = out_b[0];
        float4 o = make_float4(vx+bb, vy+bb, vz+bb, vw+bb);
        *reinterpret_cast<float4*>(y + (size_t)b*HW + s0 + (tid<<2)) = o;
    }
}

extern "C" void kernel_launch(void* const* d_in, const int* in_sizes, int n_in,
                              void* d_out, int out_size, void* d_ws, size_t ws_size,
                              hipStream_t stream)
{
    const float* inp      = (const float*)d_in[0];
    const float* origin_w = (const float*)d_in[1];
    const float* origin_b = (const float*)d_in[2];
    const float* out_w    = (const float*)d_in[3];
    const float* out_b    = (const float*)d_in[4];
    float* y  = (float*)d_out;
    float* ws = (float*)d_ws;

    float* EN = ws;                   // 4096 floats
    float* Wp = ws + EN_FLOATS;       // 20480 floats

    k0_wp   <<<81,   256, 0, stream>>>(origin_w, Wp, EN);   // pack W + zero EN
    k1_fused<<<2048, 256, 0, stream>>>(inp, Wp, origin_b, EN);
    k3_out  <<<512,  512, 0, stream>>>(inp, EN, out_w, out_b, y);
}

// Round 4
// 303.834 us; speedup vs baseline: 1.1634x; 1.1634x over previous
//
#include <hip/hip_runtime.h>
#include <math.h>

// Problem constants
#define NF 5
#define NB 8
#define NC 64
#define HW 16384
#define NK 320               // NF*NC
#define FSTRIDE (NB*NC*HW)   // elements per frame = 8388608

// ws layout (floats)
#define EN_FLOATS    (NB*NC*8)   // 4096: per (b,c): E0..E3, N0..N3

// ---------------- k0: pack origin_w; zero EN; zero y ----------------
// Wp[c>>2][k=320][4]: k1's wave owns 4 channels -> wave-uniform float4 rows
// -> scalar (s_load) weight reads. Blocks 81..144 zero y (k3 accumulates
// atomically); block 80 zeroes EN.
__global__ void k0_wp(const float* __restrict__ W, float* __restrict__ Wp,
                      float* __restrict__ EN, float* __restrict__ y){
    const int blk = blockIdx.x, tid = threadIdx.x;
    if (blk >= 81){
        // zero y: 64 blocks x 256 thr x 2 float4 = 131072 floats
        int i = (blk - 81)*256 + tid;
        float4 z = make_float4(0.f,0.f,0.f,0.f);
        reinterpret_cast<float4*>(y)[i*2]     = z;
        reinterpret_cast<float4*>(y)[i*2 + 1] = z;
        return;
    }
    if (blk == 80){
        float4 z = make_float4(0.f,0.f,0.f,0.f);
#pragma unroll
        for (int j=0; j<4; ++j)
            reinterpret_cast<float4*>(EN)[tid*4 + j] = z;
        return;
    }
    int idx = blk*256 + tid;          // 0..20479 == NC*NK
    int c = idx / NK;
    int k = idx - c*NK;
    Wp[((c>>2)*NK + k)*4 + (c&3)] = W[idx];
}

__device__ __forceinline__ float redsum64(float v){
#pragma unroll
    for (int m = 1; m < 64; m <<= 1) v += __shfl_xor(v, m, 64);
    return v;
}

// ---------------- k1: LDS-staged GEMM + E/N ----------------
// Diagnosis r0-r3: all direct-read variants cap at ~1.0-1.4 TB/s because the
// X walk is 64KB-strided in <=1KB granules (HBM channel imbalance). Fix:
// decouple HBM shape from compute shape via LDS staging with 4KB-contiguous
// row reads.
// Block = 256 thr = 4 waves; covers 16 channels x 1024-float s-window.
// Grid 512 = 8b x 16win x 4cgrp; the 4 cgrp siblings (same X panel) are
// placed on the same XCD (L2 dedup -> HBM reads input once).
// K-loop: 40 tiles of 8 rows; tile = [8][1024] floats in LDS, double-buffered
// (64 KB). Stage: thread t loads float4 at row j, s0+4t -> each row is read
// as one contiguous 4KB block-level burst. Reg-mediated (issue early, ds_write
// after compute -> HBM latency hidden under ~1100cy FMA). One barrier/tile.
// Compute: wave wv owns channels cf=cgrp*16+wv*4; lane l owns s = 4l+256jj
// (jj=0..3) -> ds_read_b128 hits all 32 banks, conflict-free. Per tile-row:
// 1 s_load float4 (W, uniform) + 4 ds_read_b128 + 64 FMA.
// Phase B: E/N from acc regs + global x4/xi (1KB/wave coalesced, L2/L3-hot),
// shfl_xor butterflies, lane0 atomics.
__global__ __launch_bounds__(256, 2) void k1_fused(
    const float* __restrict__ inp, const float* __restrict__ Wp,
    const float* __restrict__ bias, float* __restrict__ EN)
{
    __shared__ float S[2*8*1024];     // 64 KB: two 8x1024 tiles

    const int tid = threadIdx.x;
    const int l   = tid & 63;
    const int wv  = __builtin_amdgcn_readfirstlane(tid >> 6);   // 0..3
    const int blk = blockIdx.x;
    // XCD grouping: 4 cgrp siblings on one XCD
    const int xcd  = blk & 7;
    const int slot = blk >> 3;              // 0..63
    const int grp  = xcd*16 + (slot >> 2);  // 0..127 = (b, win)
    const int cgrp = slot & 3;
    const int b    = grp >> 4;
    const int s0   = (grp & 15) << 10;      // 1024-float window
    const int cf   = (cgrp << 4) + (wv << 2);                   // first of 4 ch
    const int sl   = __builtin_amdgcn_readfirstlane(cgrp*4 + wv); // W slice

    // ---- accumulators: a[ch][jj] = float4 over s = s0 + 4l + 256jj ----
    float4 a00,a01,a02,a03, a10,a11,a12,a13, a20,a21,a22,a23, a30,a31,a32,a33;
    {
        float4 bv = *reinterpret_cast<const float4*>(bias + cf);
        a00=a01=a02=a03 = make_float4(bv.x,bv.x,bv.x,bv.x);
        a10=a11=a12=a13 = make_float4(bv.y,bv.y,bv.y,bv.y);
        a20=a21=a22=a23 = make_float4(bv.z,bv.z,bv.z,bv.z);
        a30=a31=a32=a33 = make_float4(bv.w,bv.w,bv.w,bv.w);
    }

    const float* Wk = Wp + (size_t)sl*(NK*4);    // uniform base

    // global address of row K at this thread's stage slot
#define ROWP(K) (inp + ((size_t)(((K)>>6)*NB + b)*NC + ((K)&63))*HW + s0 + (tid<<2))

    float4 r0,r1,r2,r3,r4,r5,r6,r7;
#define STAGE_LOAD(KT) { int K0 = (KT)*8; \
    r0 = *reinterpret_cast<const float4*>(ROWP(K0+0)); \
    r1 = *reinterpret_cast<const float4*>(ROWP(K0+1)); \
    r2 = *reinterpret_cast<const float4*>(ROWP(K0+2)); \
    r3 = *reinterpret_cast<const float4*>(ROWP(K0+3)); \
    r4 = *reinterpret_cast<const float4*>(ROWP(K0+4)); \
    r5 = *reinterpret_cast<const float4*>(ROWP(K0+5)); \
    r6 = *reinterpret_cast<const float4*>(ROWP(K0+6)); \
    r7 = *reinterpret_cast<const float4*>(ROWP(K0+7)); }

#define STAGE_WRITE(BUF) { float* d = S + (BUF)*8192 + (tid<<2); \
    *reinterpret_cast<float4*>(d + 0*1024) = r0; \
    *reinterpret_cast<float4*>(d + 1*1024) = r1; \
    *reinterpret_cast<float4*>(d + 2*1024) = r2; \
    *reinterpret_cast<float4*>(d + 3*1024) = r3; \
    *reinterpret_cast<float4*>(d + 4*1024) = r4; \
    *reinterpret_cast<float4*>(d + 5*1024) = r5; \
    *reinterpret_cast<float4*>(d + 6*1024) = r6; \
    *reinterpret_cast<float4*>(d + 7*1024) = r7; }

#define FMA4(A, WS, XV) \
    A.x = fmaf(WS, XV.x, A.x); A.y = fmaf(WS, XV.y, A.y); \
    A.z = fmaf(WS, XV.z, A.z); A.w = fmaf(WS, XV.w, A.w);

    // prologue: tile 0
    STAGE_LOAD(0)
    STAGE_WRITE(0)

#pragma unroll 1
    for (int kt=0; kt<40; ++kt){
        __syncthreads();                       // buf[kt&1] staged; prev reads done
        if (kt < 39) STAGE_LOAD(kt+1)          // in flight under compute
        const float* X = S + (kt&1)*8192 + (l<<2);
#pragma unroll 2
        for (int k=0; k<8; ++k){
            float4 w  = *reinterpret_cast<const float4*>(Wk + ((kt*8+k)<<2));
            float4 x0 = *reinterpret_cast<const float4*>(X + k*1024);
            float4 x1 = *reinterpret_cast<const float4*>(X + k*1024 + 256);
            float4 x2 = *reinterpret_cast<const float4*>(X + k*1024 + 512);
            float4 x3 = *reinterpret_cast<const float4*>(X + k*1024 + 768);
            FMA4(a00,w.x,x0) FMA4(a01,w.x,x1) FMA4(a02,w.x,x2) FMA4(a03,w.x,x3)
            FMA4(a10,w.y,x0) FMA4(a11,w.y,x1) FMA4(a12,w.y,x2) FMA4(a13,w.y,x3)
            FMA4(a20,w.z,x0) FMA4(a21,w.z,x1) FMA4(a22,w.z,x2) FMA4(a23,w.z,x3)
            FMA4(a30,w.w,x0) FMA4(a31,w.w,x1) FMA4(a32,w.w,x2) FMA4(a33,w.w,x3)
        }
        if (kt < 39) STAGE_WRITE((kt+1)&1)     // waits the staged loads here
    }
#undef FMA4
#undef STAGE_LOAD
#undef STAGE_WRITE
#undef ROWP

    // ---- Phase B: E/N for this wave's 4 channels over the 1024-s window ----
#define PHASEB(CH, A0, A1, A2, A3) { \
    const float* p4 = inp + ((size_t)(4*NB + b)*NC + (cf+(CH)))*HW + s0 + (l<<2); \
    float4 x40 = *reinterpret_cast<const float4*>(p4); \
    float4 x41 = *reinterpret_cast<const float4*>(p4 + 256); \
    float4 x42 = *reinterpret_cast<const float4*>(p4 + 512); \
    float4 x43 = *reinterpret_cast<const float4*>(p4 + 768); \
    _Pragma("unroll") \
    for (int i=0; i<4; ++i){ \
        const float* pi = inp + ((size_t)(i*NB + b)*NC + (cf+(CH)))*HW + s0 + (l<<2); \
        float4 xi0 = *reinterpret_cast<const float4*>(pi); \
        float4 xi1 = *reinterpret_cast<const float4*>(pi + 256); \
        float4 xi2 = *reinterpret_cast<const float4*>(pi + 512); \
        float4 xi3 = *reinterpret_cast<const float4*>(pi + 768); \
        float e = 0.f, n = 0.f; \
        float dx,dy,dz,dw; \
        dx=x40.x-xi0.x; dy=x40.y-xi0.y; dz=x40.z-xi0.z; dw=x40.w-xi0.w; \
        n = fmaf(dx,dx, fmaf(dy,dy, fmaf(dz,dz, fmaf(dw,dw, n)))); \
        e = fmaf(A0.x,dx, fmaf(A0.y,dy, fmaf(A0.z,dz, fmaf(A0.w,dw, e)))); \
        dx=x41.x-xi1.x; dy=x41.y-xi1.y; dz=x41.z-xi1.z; dw=x41.w-xi1.w; \
        n = fmaf(dx,dx, fmaf(dy,dy, fmaf(dz,dz, fmaf(dw,dw, n)))); \
        e = fmaf(A1.x,dx, fmaf(A1.y,dy, fmaf(A1.z,dz, fmaf(A1.w,dw, e)))); \
        dx=x42.x-xi2.x; dy=x42.y-xi2.y; dz=x42.z-xi2.z; dw=x42.w-xi2.w; \
        n = fmaf(dx,dx, fmaf(dy,dy, fmaf(dz,dz, fmaf(dw,dw, n)))); \
        e = fmaf(A2.x,dx, fmaf(A2.y,dy, fmaf(A2.z,dz, fmaf(A2.w,dw, e)))); \
        dx=x43.x-xi3.x; dy=x43.y-xi3.y; dz=x43.z-xi3.z; dw=x43.w-xi3.w; \
        n = fmaf(dx,dx, fmaf(dy,dy, fmaf(dz,dz, fmaf(dw,dw, n)))); \
        e = fmaf(A3.x,dx, fmaf(A3.y,dy, fmaf(A3.z,dz, fmaf(A3.w,dw, e)))); \
        e = redsum64(e); n = redsum64(n); \
        if (l == 0){ \
            float* p = EN + ((size_t)b*NC + cf + (CH))*8; \
            atomicAdd(p + i,     e); \
            atomicAdd(p + 4 + i, n); \
        } \
    } }

    PHASEB(0, a00,a01,a02,a03)
    PHASEB(1, a10,a11,a12,a13)
    PHASEB(2, a20,a21,a22,a23)
    PHASEB(3, a30,a31,a32,a33)
#undef PHASEB
}

// ---------------- k3: finalize coefs + y += alpha . inp (contiguous reads) ----
// 1024 blocks = (b:8) x (s-chunk:16 of 1024 floats) x (row-group:8 of 40 rows);
// 256 thr. Per row the block reads one contiguous 4KB burst (thread t ->
// float4 at s0+4t) -- the channel-balanced HBM shape. 4 blocks/CU, 16 waves/CU,
// unroll 8. Prologue recomputes the 320 alpha coefs from EN (inlined k2).
// Finish: 4 atomicAdds/thread into zero-initialized y; bias added by rg==0.
__global__ __launch_bounds__(256, 4) void k3_out(const float* __restrict__ inp,
        const float* __restrict__ EN, const float* __restrict__ out_w,
        const float* __restrict__ out_b, float* __restrict__ y)
{
    __shared__ float Al[NK];
    const int tid = threadIdx.x;
    const int blk = blockIdx.x;
    const int b   = blk >> 7;
    const int ch  = (blk >> 3) & 15;     // s-chunk
    const int rg  = blk & 7;             // row group (40 rows)
    const int s0  = ch << 10;

    if (tid < 64){          // inline k2: coefs for channel c = tid
        const int c = tid;
        const float* e = EN + ((size_t)b*NC + c)*8;
        float w1 = out_w[c], w2 = out_w[NC + c];
        float csum = 0.f;
#pragma unroll
        for (int i=0; i<4; ++i){
            float nc = fmaxf(sqrtf(e[4+i]), 1e-12f);
            float coef = e[i] / (nc*nc);
            Al[i*NC + c] = -w1*coef;
            csum += coef;
        }
        Al[4*NC + c] = w1*csum + w2;
    }
    __syncthreads();

    float4 acc;
    if (rg == 0){ float bb = out_b[0]; acc = make_float4(bb,bb,bb,bb); }
    else        { acc = make_float4(0.f,0.f,0.f,0.f); }

    const int rbase = rg*40;
#pragma unroll 8
    for (int j=0; j<40; ++j){
        int r = rbase + j;                                   // uniform
        const float* p = inp + (size_t)(((r>>6)*NB + b)*NC + (r&63))*HW + s0 + (tid<<2);
        float  w  = Al[r];                                   // uniform broadcast
        float4 xv = *reinterpret_cast<const float4*>(p);
        acc.x = fmaf(w, xv.x, acc.x); acc.y = fmaf(w, xv.y, acc.y);
        acc.z = fmaf(w, xv.z, acc.z); acc.w = fmaf(w, xv.w, acc.w);
    }
    float* yp = y + (size_t)b*HW + s0 + (tid<<2);
    atomicAdd(yp+0, acc.x);
    atomicAdd(yp+1, acc.y);
    atomicAdd(yp+2, acc.z);
    atomicAdd(yp+3, acc.w);
}

extern "C" void kernel_launch(void* const* d_in, const int* in_sizes, int n_in,
                              void* d_out, int out_size, void* d_ws, size_t ws_size,
                              hipStream_t stream)
{
    const float* inp      = (const float*)d_in[0];
    const float* origin_w = (const float*)d_in[1];
    const float* origin_b = (const float*)d_in[2];
    const float* out_w    = (const float*)d_in[3];
    const float* out_b    = (const float*)d_in[4];
    float* y  = (float*)d_out;
    float* ws = (float*)d_ws;

    float* EN = ws;                   // 4096 floats
    float* Wp = ws + EN_FLOATS;       // 20480 floats

    k0_wp   <<<145,  256, 0, stream>>>(origin_w, Wp, EN, y);  // pack W + zero EN + zero y
    k1_fused<<<512,  256, 0, stream>>>(inp, Wp, origin_b, EN);
    k3_out  <<<1024, 256, 0, stream>>>(inp, EN, out_w, out_b, y);
}